// Round 1
// baseline (299.083 us; speedup 1.0000x reference)
//
#include <hip/hip_runtime.h>
#include <hip/hip_bf16.h>
#include <math.h>

// Problem constants
#define BATCH 32
#define CIN   256
#define HIN   28
#define WIN   28
#define NPROT 1024
#define HOUT  26
#define WOUT  26
#define MTOT  (BATCH*HOUT*WOUT)   // 21632 = 169*128
#define HWIN  (HIN*WIN)           // 784
#define KTOT  (CIN*9)             // 2304

typedef __attribute__((ext_vector_type(8))) short short8;
typedef __attribute__((ext_vector_type(4))) float f32x4;

// ---- workspace layout (bytes) ----
// xT  : [32][784][256] bf16  = 12,845,056
// pTT : [9][1024][256] bf16  =  4,718,592
// s   : [32*784] f32         =    100,352
// psq : [1024] f32           =      4,096
#define OFF_XT  ((size_t)0)
#define OFF_PTT ((size_t)12845056)
#define OFF_S   ((size_t)17563648)
#define OFF_PSQ ((size_t)17664000)
#define WS_NEED ((size_t)17668096)

__device__ __forceinline__ void gload16(const void* g, void* l) {
    // async global->LDS, 16B per lane; LDS dest is wave-uniform base + lane*16
    __builtin_amdgcn_global_load_lds((__attribute__((address_space(1))) void*)g,
                                     (__attribute__((address_space(3))) void*)l,
                                     16, 0, 0);
}

// ---- P1: x NCHW fp32 -> NHWC bf16, plus per-pixel sum of squares (no atomics) ----
__global__ void xpose_kernel(const float* __restrict__ x,
                             __hip_bfloat16* __restrict__ xT,
                             float* __restrict__ s) {
    __shared__ float tile[32][33];
    const int b = blockIdx.z, hw0 = blockIdx.x * 32;
    const int tx = threadIdx.x, ty = threadIdx.y;  // block (32,8)
    const float* xb = x + (size_t)b * CIN * HWIN;
    float ssacc = 0.f;
    for (int cg = 0; cg < 8; ++cg) {
        const int c0 = cg * 32;
        __syncthreads();
        for (int q = 0; q < 4; ++q) {
            int c = c0 + ty + q * 8, hw = hw0 + tx;
            float v = (hw < HWIN) ? xb[c * HWIN + hw] : 0.f;
            tile[ty + q * 8][tx] = v;
        }
        __syncthreads();
        for (int rq = 0; rq < 4; ++rq) {
            float v = tile[ty + rq * 8][tx];
            ssacc += v * v;   // partial over rows {ty, ty+8, ty+16, ty+24}
        }
        for (int q = 0; q < 4; ++q) {
            int hw = hw0 + ty + q * 8, c = c0 + tx;
            if (hw < HWIN)
                xT[((size_t)b * HWIN + hw) * CIN + c] = __float2bfloat16(tile[tx][ty + q * 8]);
        }
    }
    __syncthreads();
    tile[ty][tx] = ssacc;
    __syncthreads();
    if (ty == 0) {
        int hw = hw0 + tx;
        if (hw < HWIN) {
            float a = 0.f;
            for (int r = 0; r < 8; ++r) a += tile[r][tx];
            s[b * HWIN + hw] = a;
        }
    }
}

// ---- P2: prototypes OIHW fp32 -> [tap][p][c] bf16, plus ||p||^2 fp32 ----
__global__ void ppose_kernel(const float* __restrict__ proto,
                             __hip_bfloat16* __restrict__ pTT,
                             float* __restrict__ psq) {
    const int p = blockIdx.x, c = threadIdx.x;
    const float* pp = proto + ((size_t)p * CIN + c) * 9;
    float v[9]; float ss = 0.f;
    for (int t = 0; t < 9; ++t) { v[t] = pp[t]; ss += v[t] * v[t]; }
    for (int t = 0; t < 9; ++t)
        pTT[((size_t)t * NPROT + p) * CIN + c] = __float2bfloat16(v[t]);
    for (int o = 32; o > 0; o >>= 1) ss += __shfl_down(ss, o, 64);
    __shared__ float red[4];
    if ((c & 63) == 0) red[c >> 6] = ss;
    __syncthreads();
    if (c == 0) psq[p] = red[0] + red[1] + red[2] + red[3];
}

// ---- G: implicit-GEMM bf16 MFMA.  D[p][m] = sum_k proto[p][k] * patch[m][k]
// LDS layout is XOR-swizzled: row r's 16B chunk c lives at chunk slot c ^ (r&7)
// so quad reads span all 8 bank groups (residual 2-way alias is free).
// launch_bounds(256,4): VGPR<=128 -> 4-5 blocks/CU (LDS 32KB allows 5).
// Occupancy is the latency-hiding mechanism of this single-buffered loop.
__global__ __launch_bounds__(256, 4)
void gemm_kernel(const __hip_bfloat16* __restrict__ xT,
                 const __hip_bfloat16* __restrict__ pTT,
                 const float* __restrict__ s,
                 const float* __restrict__ psq,
                 float* __restrict__ out) {
    __shared__ __hip_bfloat16 Ap[128 * 64];  // proto tile [p_local][k] (swizzled)
    __shared__ __hip_bfloat16 Bx[128 * 64];  // patch tile [m_local][k] (swizzled)
    const int tid = threadIdx.x, wave = tid >> 6, lane = tid & 63;

    // XCD-aware swizzle: grid is 1D, 1352 = 169 mtiles x 8 ptiles, 1352%8==0.
    // blocks dispatch round-robin over 8 XCDs, so bid&7 == XCD id.
    // Map ptile <- XCD: all 169 blocks of one ptile share its 590KB pTT panel
    // in that XCD's private 4MB L2; consecutive bids on an XCD walk mtiles
    // contiguously so the 9-tap xT overlap re-reads also hit L2.
    const int bid = blockIdx.x;
    const int swz = (bid & 7) * 169 + (bid >> 3);   // bijective, [0,1352)
    const int n0 = (swz % 169) * 128;  // m (image-pos) tile base
    const int m0 = (swz / 169) * 128;  // p tile base (== XCD id * 128)

    const int lrow = lane >> 3;
    const int lcol = ((lane & 7) ^ lrow) * 8;   // swizzled source column

    // staging source addresses (element offsets, tap/chunk added per iter)
    int xbase[4], pbase[4];
    for (int q = 0; q < 4; ++q) {
        int rl = wave * 32 + q * 8 + lrow;
        int mm = n0 + rl;
        int bb = mm / 676, rr = mm % 676, ii = rr / WOUT, jj = rr % WOUT;
        xbase[q] = (bb * HWIN + ii * WIN + jj) * CIN + lcol;
        pbase[q] = (m0 + rl) * CIN + lcol;
    }

    f32x4 acc[4][4];
    for (int a = 0; a < 4; ++a)
        for (int b = 0; b < 4; ++b) acc[a][b] = (f32x4){0.f, 0.f, 0.f, 0.f};

    const int wr = wave >> 1, wc = wave & 1;   // wave 2x2: wr->p dir, wc->m dir
    const int quad = lane >> 4, l15 = lane & 15;
    const int swzl = l15 & 7;

    for (int t = 0; t < 9; ++t) {
        const int toffX = ((t / 3) * WIN + (t % 3)) * CIN;  // tap shift in xT
        const int toffP = t * NPROT * CIN;                  // tap plane in pTT
        for (int cc = 0; cc < CIN; cc += 64) {
            for (int q = 0; q < 4; ++q) {
                __hip_bfloat16* lA = (__hip_bfloat16*)Ap + (wave * 32 + q * 8) * 64;
                __hip_bfloat16* lB = (__hip_bfloat16*)Bx + (wave * 32 + q * 8) * 64;
                gload16(pTT + toffP + pbase[q] + cc, lA);
                gload16(xT + toffX + xbase[q] + cc, lB);
            }
            __syncthreads();
            for (int ks = 0; ks < 2; ++ks) {
                const int kc = ((ks * 4 + quad) ^ swzl) * 8;  // swizzled chunk offset
                short8 af[4], bf[4];
                for (int im = 0; im < 4; ++im)
                    af[im] = *(const short8*)&Ap[(wr * 64 + im * 16 + l15) * 64 + kc];
                for (int in = 0; in < 4; ++in)
                    bf[in] = *(const short8*)&Bx[(wc * 64 + in * 16 + l15) * 64 + kc];
                for (int im = 0; im < 4; ++im)
                    for (int in = 0; in < 4; ++in)
                        acc[im][in] = __builtin_amdgcn_mfma_f32_16x16x32_bf16(
                            af[im], bf[in], acc[im][in], 0, 0, 0);
            }
            __syncthreads();
        }
    }

    // epilogue: out[b][p][i][j] = sqrt(clip(s3 - 2C + psq)), s3 = 3x3 box of s
    for (int in = 0; in < 4; ++in) {
        int mm = n0 + wc * 64 + in * 16 + l15;
        int bb = mm / 676, rr = mm % 676, ii = rr / WOUT, jj = rr % WOUT;
        const float* sb = s + bb * HWIN + ii * WIN + jj;
        float s3v = 0.f;
        for (int di = 0; di < 3; ++di)
            for (int dj = 0; dj < 3; ++dj) s3v += sb[di * WIN + dj];
        float* ob = out + (size_t)bb * (NPROT * 676) + rr;
        for (int im = 0; im < 4; ++im) {
            int pbase_ = m0 + wr * 64 + im * 16 + quad * 4;
            for (int r = 0; r < 4; ++r) {
                int p = pbase_ + r;
                float d2 = s3v - 2.f * acc[im][in][r] + psq[p];
                ob[(size_t)p * 676] = sqrtf(fmaxf(d2, 1e-14f));
            }
        }
    }
}

// ---- fallback (only if ws too small): direct fp32 ----
__global__ void naive_kernel(const float* __restrict__ x,
                             const float* __restrict__ proto,
                             float* __restrict__ out) {
    __shared__ float patch[KTOT];
    int m = blockIdx.x;
    int b = m / 676, rr = m % 676, i = rr / WOUT, j = rr % WOUT;
    int c = threadIdx.x;
    const float* xb = x + (((size_t)b * CIN + c) * HIN + i) * WIN + j;
    for (int t = 0; t < 9; ++t) patch[c * 9 + t] = xb[(t / 3) * WIN + (t % 3)];
    __syncthreads();
    for (int pp = threadIdx.x; pp < NPROT; pp += 256) {
        const float* pr = proto + (size_t)pp * KTOT;
        float acc = 0.f;
        for (int k = 0; k < KTOT; ++k) { float d = patch[k] - pr[k]; acc += d * d; }
        out[((size_t)b * NPROT + pp) * 676 + rr] = sqrtf(fmaxf(acc, 1e-14f));
    }
}

extern "C" void kernel_launch(void* const* d_in, const int* in_sizes, int n_in,
                              void* d_out, int out_size, void* d_ws, size_t ws_size,
                              hipStream_t stream) {
    const float* x = (const float*)d_in[0];
    const float* proto = (const float*)d_in[1];
    float* out = (float*)d_out;

    if (ws_size < WS_NEED) {
        naive_kernel<<<MTOT, 256, 0, stream>>>(x, proto, out);
        return;
    }

    char* ws = (char*)d_ws;
    __hip_bfloat16* xT  = (__hip_bfloat16*)(ws + OFF_XT);
    __hip_bfloat16* pTT = (__hip_bfloat16*)(ws + OFF_PTT);
    float* s   = (float*)(ws + OFF_S);
    float* psq = (float*)(ws + OFF_PSQ);

    xpose_kernel<<<dim3(25, 1, BATCH), dim3(32, 8), 0, stream>>>(x, xT, s);
    ppose_kernel<<<NPROT, 256, 0, stream>>>(proto, pTT, psq);
    gemm_kernel<<<dim3(1352), 256, 0, stream>>>(xT, pTT, s, psq, out);
}

// Round 2
// 255.791 us; speedup vs baseline: 1.1692x; 1.1692x over previous
//
#include <hip/hip_runtime.h>
#include <hip/hip_bf16.h>
#include <math.h>

// Problem constants
#define BATCH 32
#define CIN   256
#define HIN   28
#define WIN   28
#define NPROT 1024
#define HOUT  26
#define WOUT  26
#define MTOT  (BATCH*HOUT*WOUT)   // 21632 = 169*128
#define HWIN  (HIN*WIN)           // 784
#define KTOT  (CIN*9)             // 2304
#define NKT   36                  // K-tiles of 64: 9 taps x 4 chunks

typedef __attribute__((ext_vector_type(8))) short short8;
typedef __attribute__((ext_vector_type(4))) float f32x4;

// ---- workspace layout (bytes) ----
// xT  : [32][784][256] bf16  = 12,845,056
// pTT : [9][1024][256] bf16  =  4,718,592
// s   : [32*784] f32         =    100,352
// psq : [1024] f32           =      4,096
#define OFF_XT  ((size_t)0)
#define OFF_PTT ((size_t)12845056)
#define OFF_S   ((size_t)17563648)
#define OFF_PSQ ((size_t)17664000)
#define WS_NEED ((size_t)17668096)

__device__ __forceinline__ void gload16(const void* g, void* l) {
    // async global->LDS, 16B per lane; LDS dest is wave-uniform base + lane*16
    __builtin_amdgcn_global_load_lds((__attribute__((address_space(1))) void*)g,
                                     (__attribute__((address_space(3))) void*)l,
                                     16, 0, 0);
}

// ---- P1: x NCHW fp32 -> NHWC bf16, plus per-pixel sum of squares (no atomics) ----
__global__ void xpose_kernel(const float* __restrict__ x,
                             __hip_bfloat16* __restrict__ xT,
                             float* __restrict__ s) {
    __shared__ float tile[32][33];
    const int b = blockIdx.z, hw0 = blockIdx.x * 32;
    const int tx = threadIdx.x, ty = threadIdx.y;  // block (32,8)
    const float* xb = x + (size_t)b * CIN * HWIN;
    float ssacc = 0.f;
    for (int cg = 0; cg < 8; ++cg) {
        const int c0 = cg * 32;
        __syncthreads();
        for (int q = 0; q < 4; ++q) {
            int c = c0 + ty + q * 8, hw = hw0 + tx;
            float v = (hw < HWIN) ? xb[c * HWIN + hw] : 0.f;
            tile[ty + q * 8][tx] = v;
        }
        __syncthreads();
        for (int rq = 0; rq < 4; ++rq) {
            float v = tile[ty + rq * 8][tx];
            ssacc += v * v;   // partial over rows {ty, ty+8, ty+16, ty+24}
        }
        for (int q = 0; q < 4; ++q) {
            int hw = hw0 + ty + q * 8, c = c0 + tx;
            if (hw < HWIN)
                xT[((size_t)b * HWIN + hw) * CIN + c] = __float2bfloat16(tile[tx][ty + q * 8]);
        }
    }
    __syncthreads();
    tile[ty][tx] = ssacc;
    __syncthreads();
    if (ty == 0) {
        int hw = hw0 + tx;
        if (hw < HWIN) {
            float a = 0.f;
            for (int r = 0; r < 8; ++r) a += tile[r][tx];
            s[b * HWIN + hw] = a;
        }
    }
}

// ---- P2: prototypes OIHW fp32 -> [tap][p][c] bf16, plus ||p||^2 fp32 ----
__global__ void ppose_kernel(const float* __restrict__ proto,
                             __hip_bfloat16* __restrict__ pTT,
                             float* __restrict__ psq) {
    const int p = blockIdx.x, c = threadIdx.x;
    const float* pp = proto + ((size_t)p * CIN + c) * 9;
    float v[9]; float ss = 0.f;
    for (int t = 0; t < 9; ++t) { v[t] = pp[t]; ss += v[t] * v[t]; }
    for (int t = 0; t < 9; ++t)
        pTT[((size_t)t * NPROT + p) * CIN + c] = __float2bfloat16(v[t]);
    for (int o = 32; o > 0; o >>= 1) ss += __shfl_down(ss, o, 64);
    __shared__ float red[4];
    if ((c & 63) == 0) red[c >> 6] = ss;
    __syncthreads();
    if (c == 0) psq[p] = red[0] + red[1] + red[2] + red[3];
}

// ---- G: implicit-GEMM bf16 MFMA, counted-vmcnt 3-deep K-tile pipeline.
// D[p][m] = sum_k proto[p][k] * patch[m][k]
// Tile: BM=256(p) x BN=128(m) x BK=64. 8 waves (4p x 2m), per-wave 64x64.
// LDS: 3 K-tile buffers of (A[256][64] + B[128][64]) bf16 = 3 x 48KB = 144KB.
// While computing K-tile kt from buf[kt%3], stage kt+2 into buf[(kt+2)%3]
// (never the compute buffer) -> boundary wait is vmcnt(6): only kt+2's own
// 6 loads stay outstanding, everything older (incl. kt+1) has landed.
// Loads thus remain in flight ACROSS barriers (T3+T4); setprio around the
// MFMA cluster (T5) exploits the resulting wave role-split.
// LDS rows XOR-swizzled: row r's 16B chunk c at slot c^(r&7) (zero conflicts,
// verified by SQ_LDS_BANK_CONFLICT=0 on the previous kernel).
__global__ __launch_bounds__(512, 2)
void gemm_kernel(const __hip_bfloat16* __restrict__ xT,
                 const __hip_bfloat16* __restrict__ pTT,
                 const float* __restrict__ s,
                 const float* __restrict__ psq,
                 float* __restrict__ out) {
    __shared__ __hip_bfloat16 lds[3 * 24576];   // 147456 B
    const int tid = threadIdx.x, wave = tid >> 6, lane = tid & 63;
    const int n0 = blockIdx.x * 128;   // m tile base (169 tiles, exact)
    const int m0 = blockIdx.y * 256;   // p tile base (4 tiles, exact)
    const int lrow = lane >> 3;
    const int lcol = ((lane & 7) ^ lrow) * 8;   // pre-swizzled source chunk col

    // per-wave staging source bases (element offsets; tap/chunk added per kt)
    int pbase[4], xbase[2];
#pragma unroll
    for (int q = 0; q < 4; ++q) {
        int row = wave * 32 + q * 8 + lrow;     // A row in [0,256)
        pbase[q] = (m0 + row) * CIN + lcol;
    }
#pragma unroll
    for (int q = 0; q < 2; ++q) {
        int row = wave * 16 + q * 8 + lrow;     // B row in [0,128)
        int mm = n0 + row;
        int bb = mm / 676, rr = mm % 676, ii = rr / WOUT, jj = rr % WOUT;
        xbase[q] = (bb * HWIN + ii * WIN + jj) * CIN + lcol;
    }

    // issue half of K-tile kt's staging: ph=0 -> A rows q0,q1 + B rows q0;
    // ph=1 -> A rows q2,q3 + B rows q1.  3 gloads per call, 6 per K-tile.
    auto stage = [&](int kt, int buf, int ph) {
        const int tap = kt >> 2, cc = (kt & 3) * 64;
        const __hip_bfloat16* srcP = pTT + tap * (NPROT * CIN) + cc;
        const __hip_bfloat16* srcX = xT + ((tap / 3) * WIN + (tap % 3)) * CIN + cc;
        __hip_bfloat16* base = (__hip_bfloat16*)lds + buf * 24576;
        const int q0 = ph * 2;
        gload16(srcP + pbase[q0] + 0,     base + (wave * 32 + (q0    ) * 8) * 64);
        gload16(srcP + pbase[q0 + 1] + 0, base + (wave * 32 + (q0 + 1) * 8) * 64);
        gload16(srcX + xbase[ph] + 0,     base + 16384 + (wave * 16 + ph * 8) * 64);
    };

    f32x4 acc[4][4];
#pragma unroll
    for (int a = 0; a < 4; ++a)
#pragma unroll
        for (int b = 0; b < 4; ++b) acc[a][b] = (f32x4){0.f, 0.f, 0.f, 0.f};

    const int wr = wave >> 1, wc = wave & 1;   // 4 p-rows x 2 m-cols of waves
    const int quad = lane >> 4, l15 = lane & 15, sw = l15 & 7;

    // prologue: fully stage K-tiles 0 and 1; wait for tile 0 only.
    stage(0, 0, 0); stage(0, 0, 1);
    stage(1, 1, 0); stage(1, 1, 1);
    asm volatile("s_waitcnt vmcnt(6)" ::: "memory");
    __builtin_amdgcn_s_barrier();

#pragma unroll 3
    for (int kt = 0; kt < NKT; ++kt) {
        const int cb = kt % 3;
        const __hip_bfloat16* A = (const __hip_bfloat16*)lds + cb * 24576;
        const __hip_bfloat16* B = A + 16384;
        const bool st = (kt + 2) < NKT;
        const int sb = (kt + 2) % 3;

        // ---- phase 0 : kstep 0 (chunks 0..3) ----
        {
            short8 af[4], bf[4];
#pragma unroll
            for (int im = 0; im < 4; ++im)
                af[im] = *(const short8*)&A[(wr * 64 + im * 16 + l15) * 64 + ((quad) ^ sw) * 8];
#pragma unroll
            for (int in = 0; in < 4; ++in)
                bf[in] = *(const short8*)&B[(wc * 64 + in * 16 + l15) * 64 + ((quad) ^ sw) * 8];
            if (st) stage(kt + 2, sb, 0);
            __builtin_amdgcn_s_barrier();
            __builtin_amdgcn_s_setprio(1);
#pragma unroll
            for (int im = 0; im < 4; ++im)
#pragma unroll
                for (int in = 0; in < 4; ++in)
                    acc[im][in] = __builtin_amdgcn_mfma_f32_16x16x32_bf16(
                        af[im], bf[in], acc[im][in], 0, 0, 0);
            __builtin_amdgcn_s_setprio(0);
            __builtin_amdgcn_s_barrier();
        }
        // ---- phase 1 : kstep 1 (chunks 4..7), K-tile boundary ----
        {
            short8 af[4], bf[4];
#pragma unroll
            for (int im = 0; im < 4; ++im)
                af[im] = *(const short8*)&A[(wr * 64 + im * 16 + l15) * 64 + ((4 + quad) ^ sw) * 8];
#pragma unroll
            for (int in = 0; in < 4; ++in)
                bf[in] = *(const short8*)&B[(wc * 64 + in * 16 + l15) * 64 + ((4 + quad) ^ sw) * 8];
            if (st) stage(kt + 2, sb, 1);
            // boundary: ensure kt+1 (staged during kt-1) has fully landed.
            // steady state leaves exactly kt+2's 6 loads outstanding.
            if (kt < NKT - 2) asm volatile("s_waitcnt vmcnt(6)" ::: "memory");
            else              asm volatile("s_waitcnt vmcnt(0)" ::: "memory");
            __builtin_amdgcn_s_barrier();
            __builtin_amdgcn_s_setprio(1);
#pragma unroll
            for (int im = 0; im < 4; ++im)
#pragma unroll
                for (int in = 0; in < 4; ++in)
                    acc[im][in] = __builtin_amdgcn_mfma_f32_16x16x32_bf16(
                        af[im], bf[in], acc[im][in], 0, 0, 0);
            __builtin_amdgcn_s_setprio(0);
            __builtin_amdgcn_s_barrier();
        }
    }

    // epilogue: out[b][p][i][j] = sqrt(clip(s3 - 2C + psq)), s3 = 3x3 box of s
#pragma unroll
    for (int in = 0; in < 4; ++in) {
        int mm = n0 + wc * 64 + in * 16 + l15;
        int bb = mm / 676, rr = mm % 676, ii = rr / WOUT, jj = rr % WOUT;
        const float* sb = s + bb * HWIN + ii * WIN + jj;
        float s3v = 0.f;
#pragma unroll
        for (int di = 0; di < 3; ++di)
#pragma unroll
            for (int dj = 0; dj < 3; ++dj) s3v += sb[di * WIN + dj];
        float* ob = out + (size_t)bb * (NPROT * 676) + rr;
#pragma unroll
        for (int im = 0; im < 4; ++im) {
            int pbase_ = m0 + wr * 64 + im * 16 + quad * 4;
#pragma unroll
            for (int r = 0; r < 4; ++r) {
                int p = pbase_ + r;
                float d2 = s3v - 2.f * acc[im][in][r] + psq[p];
                ob[(size_t)p * 676] = sqrtf(fmaxf(d2, 1e-14f));
            }
        }
    }
}

// ---- fallback (only if ws too small): direct fp32 ----
__global__ void naive_kernel(const float* __restrict__ x,
                             const float* __restrict__ proto,
                             float* __restrict__ out) {
    __shared__ float patch[KTOT];
    int m = blockIdx.x;
    int b = m / 676, rr = m % 676, i = rr / WOUT, j = rr % WOUT;
    int c = threadIdx.x;
    const float* xb = x + (((size_t)b * CIN + c) * HIN + i) * WIN + j;
    for (int t = 0; t < 9; ++t) patch[c * 9 + t] = xb[(t / 3) * WIN + (t % 3)];
    __syncthreads();
    for (int pp = threadIdx.x; pp < NPROT; pp += 256) {
        const float* pr = proto + (size_t)pp * KTOT;
        float acc = 0.f;
        for (int k = 0; k < KTOT; ++k) { float d = patch[k] - pr[k]; acc += d * d; }
        out[((size_t)b * NPROT + pp) * 676 + rr] = sqrtf(fmaxf(acc, 1e-14f));
    }
}

extern "C" void kernel_launch(void* const* d_in, const int* in_sizes, int n_in,
                              void* d_out, int out_size, void* d_ws, size_t ws_size,
                              hipStream_t stream) {
    const float* x = (const float*)d_in[0];
    const float* proto = (const float*)d_in[1];
    float* out = (float*)d_out;

    if (ws_size < WS_NEED) {
        naive_kernel<<<MTOT, 256, 0, stream>>>(x, proto, out);
        return;
    }

    char* ws = (char*)d_ws;
    __hip_bfloat16* xT  = (__hip_bfloat16*)(ws + OFF_XT);
    __hip_bfloat16* pTT = (__hip_bfloat16*)(ws + OFF_PTT);
    float* s   = (float*)(ws + OFF_S);
    float* psq = (float*)(ws + OFF_PSQ);

    xpose_kernel<<<dim3(25, 1, BATCH), dim3(32, 8), 0, stream>>>(x, xT, s);
    ppose_kernel<<<NPROT, 256, 0, stream>>>(proto, pTT, psq);
    gemm_kernel<<<dim3(169, 4), 512, 0, stream>>>(xT, pTT, s, psq, out);
}

// Round 3
// 244.089 us; speedup vs baseline: 1.2253x; 1.0479x over previous
//
#include <hip/hip_runtime.h>
#include <hip/hip_bf16.h>
#include <math.h>

// Problem constants
#define BATCH 32
#define CIN   256
#define HIN   28
#define WIN   28
#define NPROT 1024
#define HOUT  26
#define WOUT  26
#define MTOT  (BATCH*HOUT*WOUT)   // 21632 = 169*128
#define HWIN  (HIN*WIN)           // 784
#define KTOT  (CIN*9)             // 2304
#define NKT   36                  // K-tiles of 64: 9 taps x 4 chunks

typedef __attribute__((ext_vector_type(8))) short short8;
typedef __attribute__((ext_vector_type(4))) float f32x4;

// ---- workspace layout (bytes) ----
// xT  : [32][784][256] bf16  = 12,845,056
// pTT : [9][1024][256] bf16  =  4,718,592
// s   : [32*784] f32         =    100,352
// psq : [1024] f32           =      4,096
#define OFF_XT  ((size_t)0)
#define OFF_PTT ((size_t)12845056)
#define OFF_S   ((size_t)17563648)
#define OFF_PSQ ((size_t)17664000)
#define WS_NEED ((size_t)17668096)

__device__ __forceinline__ void gload16(const void* g, void* l) {
    // async global->LDS, 16B per lane; LDS dest is wave-uniform base + lane*16
    __builtin_amdgcn_global_load_lds((__attribute__((address_space(1))) void*)g,
                                     (__attribute__((address_space(3))) void*)l,
                                     16, 0, 0);
}

// ---- P1: x NCHW fp32 -> NHWC bf16, plus per-pixel sum of squares (no atomics) ----
__global__ void xpose_kernel(const float* __restrict__ x,
                             __hip_bfloat16* __restrict__ xT,
                             float* __restrict__ s) {
    __shared__ float tile[32][33];
    const int b = blockIdx.z, hw0 = blockIdx.x * 32;
    const int tx = threadIdx.x, ty = threadIdx.y;  // block (32,8)
    const float* xb = x + (size_t)b * CIN * HWIN;
    float ssacc = 0.f;
    for (int cg = 0; cg < 8; ++cg) {
        const int c0 = cg * 32;
        __syncthreads();
        for (int q = 0; q < 4; ++q) {
            int c = c0 + ty + q * 8, hw = hw0 + tx;
            float v = (hw < HWIN) ? xb[c * HWIN + hw] : 0.f;
            tile[ty + q * 8][tx] = v;
        }
        __syncthreads();
        for (int rq = 0; rq < 4; ++rq) {
            float v = tile[ty + rq * 8][tx];
            ssacc += v * v;   // partial over rows {ty, ty+8, ty+16, ty+24}
        }
        for (int q = 0; q < 4; ++q) {
            int hw = hw0 + ty + q * 8, c = c0 + tx;
            if (hw < HWIN)
                xT[((size_t)b * HWIN + hw) * CIN + c] = __float2bfloat16(tile[tx][ty + q * 8]);
        }
    }
    __syncthreads();
    tile[ty][tx] = ssacc;
    __syncthreads();
    if (ty == 0) {
        int hw = hw0 + tx;
        if (hw < HWIN) {
            float a = 0.f;
            for (int r = 0; r < 8; ++r) a += tile[r][tx];
            s[b * HWIN + hw] = a;
        }
    }
}

// ---- P2: prototypes OIHW fp32 -> [tap][p][c] bf16, plus ||p||^2 fp32 ----
__global__ void ppose_kernel(const float* __restrict__ proto,
                             __hip_bfloat16* __restrict__ pTT,
                             float* __restrict__ psq) {
    const int p = blockIdx.x, c = threadIdx.x;
    const float* pp = proto + ((size_t)p * CIN + c) * 9;
    float v[9]; float ss = 0.f;
    for (int t = 0; t < 9; ++t) { v[t] = pp[t]; ss += v[t] * v[t]; }
    for (int t = 0; t < 9; ++t)
        pTT[((size_t)t * NPROT + p) * CIN + c] = __float2bfloat16(v[t]);
    for (int o = 32; o > 0; o >>= 1) ss += __shfl_down(ss, o, 64);
    __shared__ float red[4];
    if ((c & 63) == 0) red[c >> 6] = ss;
    __syncthreads();
    if (c == 0) psq[p] = red[0] + red[1] + red[2] + red[3];
}

// ---- G: implicit-GEMM bf16 MFMA, 2-deep counted staging pipeline.
// D[p][m] = sum_k proto[p][k] * patch[m][k]
// Tile: 128(p) x 128(m) x BK=64. 4 waves (2x2), per-wave 64x64 via 4x4
// 16x16x32 fragments (round-0's verified layout).
// LDS: 2 buffers x (A[128][64] + B[128][64]) bf16 = 2 x 32KB = 64KB
//   -> 2 blocks/CU (cross-block overlap preserved, = round-0 occupancy).
// Pipeline per K-tile kt: issue kt+1's 8 global_load_lds FIRST, then
// compute kt from the other buffer (16 ds_read_b128 + 32 MFMA), THEN wait
// vmcnt(0) (kt+1's loads have had the whole compute phase to land) and
// one raw s_barrier. This removes round-0's drain-right-after-issue
// (full L2 latency exposed every chunk) and halves the barrier count.
// LDS rows XOR-swizzled: row r's 16B chunk c at slot c^(r&7)
// (SQ_LDS_BANK_CONFLICT == 0 verified in rounds 0-2).
__global__ __launch_bounds__(256, 2)
void gemm_kernel(const __hip_bfloat16* __restrict__ xT,
                 const __hip_bfloat16* __restrict__ pTT,
                 const float* __restrict__ s,
                 const float* __restrict__ psq,
                 float* __restrict__ out) {
    __shared__ __hip_bfloat16 lds[2][16384];  // [buf][ A:0..8191 | B:8192..16383 ]
    const int tid = threadIdx.x, wave = tid >> 6, lane = tid & 63;
    const int n0 = blockIdx.x * 128;  // m (image-pos) tile base
    const int m0 = blockIdx.y * 128;  // p tile base
    const int lrow = lane >> 3;
    const int lcol = ((lane & 7) ^ lrow) * 8;   // pre-swizzled source chunk col

    // staging source addresses (element offsets; tap/chunk added per K-tile)
    int xbase[4], pbase[4];
#pragma unroll
    for (int q = 0; q < 4; ++q) {
        int rl = wave * 32 + q * 8 + lrow;
        int mm = n0 + rl;
        int bb = mm / 676, rr = mm % 676, ii = rr / WOUT, jj = rr % WOUT;
        xbase[q] = (bb * HWIN + ii * WIN + jj) * CIN + lcol;
        pbase[q] = (m0 + rl) * CIN + lcol;
    }

    // stage K-tile kt into buffer buf: 8 global_load_lds per wave
    auto stage = [&](int kt, int buf) {
        const int tap = kt >> 2, cc = (kt & 3) * 64;
        const __hip_bfloat16* srcP = pTT + (size_t)tap * (NPROT * CIN) + cc;
        const __hip_bfloat16* srcX = xT + ((tap / 3) * WIN + (tap % 3)) * CIN + cc;
        __hip_bfloat16* base = &lds[buf][0];
#pragma unroll
        for (int q = 0; q < 4; ++q) {
            gload16(srcP + pbase[q], base + (wave * 32 + q * 8) * 64);
            gload16(srcX + xbase[q], base + 8192 + (wave * 32 + q * 8) * 64);
        }
    };

    f32x4 acc[4][4];
#pragma unroll
    for (int a = 0; a < 4; ++a)
#pragma unroll
        for (int b = 0; b < 4; ++b) acc[a][b] = (f32x4){0.f, 0.f, 0.f, 0.f};

    const int wr = wave >> 1, wc = wave & 1;   // wave 2x2: wr->p dir, wc->m dir
    const int quad = lane >> 4, l15 = lane & 15;
    const int sw = l15 & 7;

    // prologue: stage tile 0, wait, barrier
    stage(0, 0);
    asm volatile("s_waitcnt vmcnt(0)" ::: "memory");
    __builtin_amdgcn_s_barrier();

#pragma unroll 2
    for (int kt = 0; kt < NKT; ++kt) {
        const int cur = kt & 1;
        const bool st = (kt + 1) < NKT;
        if (st) stage(kt + 1, cur ^ 1);      // issue next tile's loads FIRST

        const __hip_bfloat16* A = &lds[cur][0];
        const __hip_bfloat16* B = &lds[cur][8192];
#pragma unroll
        for (int ks = 0; ks < 2; ++ks) {
            const int kc = ((ks * 4 + quad) ^ sw) * 8;  // swizzled chunk offset
            short8 af[4], bf[4];
#pragma unroll
            for (int im = 0; im < 4; ++im)
                af[im] = *(const short8*)&A[(wr * 64 + im * 16 + l15) * 64 + kc];
#pragma unroll
            for (int in = 0; in < 4; ++in)
                bf[in] = *(const short8*)&B[(wc * 64 + in * 16 + l15) * 64 + kc];
#pragma unroll
            for (int im = 0; im < 4; ++im)
#pragma unroll
                for (int in = 0; in < 4; ++in)
                    acc[im][in] = __builtin_amdgcn_mfma_f32_16x16x32_bf16(
                        af[im], bf[in], acc[im][in], 0, 0, 0);
        }

        if (st) {
            // kt+1's 8 loads were issued before the compute above; by now
            // their latency is covered. Drain them and flip.
            asm volatile("s_waitcnt vmcnt(0)" ::: "memory");
            __builtin_amdgcn_s_barrier();
        }
    }

    // epilogue: out[b][p][i][j] = sqrt(clip(s3 - 2C + psq)), s3 = 3x3 box of s
#pragma unroll
    for (int in = 0; in < 4; ++in) {
        int mm = n0 + wc * 64 + in * 16 + l15;
        int bb = mm / 676, rr = mm % 676, ii = rr / WOUT, jj = rr % WOUT;
        const float* sb = s + bb * HWIN + ii * WIN + jj;
        float s3v = 0.f;
#pragma unroll
        for (int di = 0; di < 3; ++di)
#pragma unroll
            for (int dj = 0; dj < 3; ++dj) s3v += sb[di * WIN + dj];
        float* ob = out + (size_t)bb * (NPROT * 676) + rr;
#pragma unroll
        for (int im = 0; im < 4; ++im) {
            int pbase_ = m0 + wr * 64 + im * 16 + quad * 4;
#pragma unroll
            for (int r = 0; r < 4; ++r) {
                int p = pbase_ + r;
                float d2 = s3v - 2.f * acc[im][in][r] + psq[p];
                ob[(size_t)p * 676] = sqrtf(fmaxf(d2, 1e-14f));
            }
        }
    }
}

// ---- fallback (only if ws too small): direct fp32 ----
__global__ void naive_kernel(const float* __restrict__ x,
                             const float* __restrict__ proto,
                             float* __restrict__ out) {
    __shared__ float patch[KTOT];
    int m = blockIdx.x;
    int b = m / 676, rr = m % 676, i = rr / WOUT, j = rr % WOUT;
    int c = threadIdx.x;
    const float* xb = x + (((size_t)b * CIN + c) * HIN + i) * WIN + j;
    for (int t = 0; t < 9; ++t) patch[c * 9 + t] = xb[(t / 3) * WIN + (t % 3)];
    __syncthreads();
    for (int pp = threadIdx.x; pp < NPROT; pp += 256) {
        const float* pr = proto + (size_t)pp * KTOT;
        float acc = 0.f;
        for (int k = 0; k < KTOT; ++k) { float d = patch[k] - pr[k]; acc += d * d; }
        out[((size_t)b * NPROT + pp) * 676 + rr] = sqrtf(fmaxf(acc, 1e-14f));
    }
}

extern "C" void kernel_launch(void* const* d_in, const int* in_sizes, int n_in,
                              void* d_out, int out_size, void* d_ws, size_t ws_size,
                              hipStream_t stream) {
    const float* x = (const float*)d_in[0];
    const float* proto = (const float*)d_in[1];
    float* out = (float*)d_out;

    if (ws_size < WS_NEED) {
        naive_kernel<<<MTOT, 256, 0, stream>>>(x, proto, out);
        return;
    }

    char* ws = (char*)d_ws;
    __hip_bfloat16* xT  = (__hip_bfloat16*)(ws + OFF_XT);
    __hip_bfloat16* pTT = (__hip_bfloat16*)(ws + OFF_PTT);
    float* s   = (float*)(ws + OFF_S);
    float* psq = (float*)(ws + OFF_PSQ);

    xpose_kernel<<<dim3(25, 1, BATCH), dim3(32, 8), 0, stream>>>(x, xT, s);
    ppose_kernel<<<NPROT, 256, 0, stream>>>(proto, pTT, psq);
    gemm_kernel<<<dim3(169, 8), 256, 0, stream>>>(xT, pTT, s, psq, out);
}